// Round 1
// baseline (423.298 us; speedup 1.0000x reference)
//
#include <hip/hip_runtime.h>
#include <hip/hip_bf16.h>

// Reduction of the reference (h0 = 0):
//   z  = sigmoid(x @ Wz + bz),  Wz = (w_z[0]+w_z[1])[:256,:]
//   t  = tanh   (x @ Wh + bh),  Wh = (w_h[0]+w_h[1])[:256,:]
//   h  = (1-z) * t
//   hid= relu(h @ fc1_w + fc1_b)
//   out= sigmoid(hid @ fc2_w + fc2_b)
// w_r/b_r and edge_index are dead. Main cost: [100000,256] @ [256,64] fp32.

#define NF   256   // node features (K dim)
#define NOUT 64    // 32 z-gate cols | 32 h-tilde cols
#define TN   128   // nodes per block == threads per block
#define BK   32    // K-chunk staged in LDS
#define LDS_STRIDE (BK + 1)  // 33: lane stride 33 % 32 == 1 -> conflict-free

// ---- prep: fold the two diffusion-direction weight matrices into W[256][64]
__global__ void prep_W(const float* __restrict__ wz,   // (2, 288, 32)
                       const float* __restrict__ wh,   // (2, 288, 32)
                       float* __restrict__ W)          // [256][64] row-major
{
    int idx = blockIdx.x * blockDim.x + threadIdx.x;   // 0 .. 16383
    if (idx >= NF * NOUT) return;
    int k = idx >> 6;          // feature row, 0..255
    int o = idx & 63;          // output col, 0..63
    const int PLANE = 288 * 32;
    float v;
    if (o < 32) v = wz[k * 32 + o]        + wz[PLANE + k * 32 + o];
    else        v = wh[k * 32 + (o - 32)] + wh[PLANE + k * 32 + (o - 32)];
    W[idx] = v;
}

__device__ __forceinline__ float fast_sigmoid(float v) {
    return 1.0f / (1.0f + __expf(-v));
}
__device__ __forceinline__ float fast_tanh(float v) {
    // tanh(v) = 1 - 2/(exp(2v)+1); saturates correctly at +/-1 for large |v|
    return 1.0f - 2.0f / (1.0f + __expf(2.0f * v));
}

__global__ void rgcn_main(const float* __restrict__ x,     // [N, 256]
                          const float* __restrict__ W,     // [256][64] (ws)
                          const float* __restrict__ bz,    // [32]
                          const float* __restrict__ bh,    // [32]
                          const float* __restrict__ fc1w,  // [32][32] (in,out)
                          const float* __restrict__ fc1b,  // [32]
                          const float* __restrict__ fc2w,  // [32]
                          const float* __restrict__ fc2b,  // [1]
                          float* __restrict__ out,         // [N]
                          int n_nodes)
{
    __shared__ float Xs[TN * LDS_STRIDE];

    const int tid   = threadIdx.x;
    const int node0 = blockIdx.x * TN;
    const int node  = node0 + tid;

    float acc[NOUT];
#pragma unroll
    for (int i = 0; i < NOUT; ++i) acc[i] = 0.0f;

    for (int k0 = 0; k0 < NF; k0 += BK) {
        __syncthreads();
        // Stage TN x BK tile. TN*BK/4 = TN*8 float4s; 8 per thread.
        // q -> (node q>>3, float4-slot q&7): 8 consecutive lanes read one
        // 128 B row segment -> fully coalesced cache-line loads.
#pragma unroll
        for (int i = 0; i < 8; ++i) {
            int q  = tid + i * TN;
            int nn = q >> 3;
            int kk = q & 7;
            float4 v = make_float4(0.f, 0.f, 0.f, 0.f);
            int gn = node0 + nn;
            if (gn < n_nodes)
                v = *(const float4*)(x + (size_t)gn * NF + k0 + kk * 4);
            float* dst = &Xs[nn * LDS_STRIDE + kk * 4];
            dst[0] = v.x; dst[1] = v.y; dst[2] = v.z; dst[3] = v.w;
        }
        __syncthreads();

#pragma unroll 2
        for (int k = 0; k < BK; ++k) {
            float a = Xs[tid * LDS_STRIDE + k];
            const float4* wr = (const float4*)(W + (size_t)(k0 + k) * NOUT);
#pragma unroll
            for (int o4 = 0; o4 < 16; ++o4) {
                float4 w = wr[o4];          // wave-uniform -> scalar/broadcast
                acc[o4 * 4 + 0] = fmaf(a, w.x, acc[o4 * 4 + 0]);
                acc[o4 * 4 + 1] = fmaf(a, w.y, acc[o4 * 4 + 1]);
                acc[o4 * 4 + 2] = fmaf(a, w.z, acc[o4 * 4 + 2]);
                acc[o4 * 4 + 3] = fmaf(a, w.w, acc[o4 * 4 + 3]);
            }
        }
    }

    if (node < n_nodes) {
        // gates + GRU combine (h0 = 0)
        float h[32];
#pragma unroll
        for (int o = 0; o < 32; ++o) {
            float z = fast_sigmoid(acc[o]      + bz[o]);
            float t = fast_tanh   (acc[32 + o] + bh[o]);
            h[o] = (1.0f - z) * t;
        }
        // fc head: relu(h @ fc1) @ fc2 -> sigmoid
        float oacc = fc2b[0];
        for (int j = 0; j < 32; ++j) {
            float s = fc1b[j];
#pragma unroll
            for (int o = 0; o < 32; ++o)
                s = fmaf(h[o], fc1w[o * 32 + j], s);
            s = fmaxf(s, 0.0f);
            oacc = fmaf(s, fc2w[j], oacc);
        }
        out[node] = fast_sigmoid(oacc);
    }
}

extern "C" void kernel_launch(void* const* d_in, const int* in_sizes, int n_in,
                              void* d_out, int out_size, void* d_ws, size_t ws_size,
                              hipStream_t stream) {
    // setup_inputs order:
    // 0:x 1:edge_index(dead) 2:w_z 3:b_z 4:w_r(dead) 5:b_r(dead)
    // 6:w_h 7:b_h 8:fc1_w 9:fc1_b 10:fc2_w 11:fc2_b
    const float* x    = (const float*)d_in[0];
    const float* wz   = (const float*)d_in[2];
    const float* bz   = (const float*)d_in[3];
    const float* wh   = (const float*)d_in[6];
    const float* bh   = (const float*)d_in[7];
    const float* fc1w = (const float*)d_in[8];
    const float* fc1b = (const float*)d_in[9];
    const float* fc2w = (const float*)d_in[10];
    const float* fc2b = (const float*)d_in[11];
    float* out = (float*)d_out;
    float* W   = (float*)d_ws;   // 256*64*4 = 64 KB

    const int n = in_sizes[0] / NF;   // 100000

    prep_W<<<(NF * NOUT + 255) / 256, 256, 0, stream>>>(wz, wh, W);
    rgcn_main<<<(n + TN - 1) / TN, TN, 0, stream>>>(
        x, W, bz, bh, fc1w, fc1b, fc2w, fc2b, out, n);
}

// Round 2
// 247.041 us; speedup vs baseline: 1.7135x; 1.7135x over previous
//
#include <hip/hip_runtime.h>
#include <hip/hip_bf16.h>

// Reduction of the reference (h0 = 0):
//   z  = sigmoid(x @ Wz + bz),  Wz = (w_z[0]+w_z[1])[:256,:]
//   t  = tanh   (x @ Wh + bh),  Wh = (w_h[0]+w_h[1])[:256,:]
//   h  = (1-z) * t
//   hid= relu(h @ fc1_w + fc1_b)
//   out= sigmoid(hid @ fc2_w + fc2_b)
// w_r/b_r and edge_index are dead. Main cost: [100000,256] @ [256,64] fp32.
//
// R1 post-mortem: acc[64]/thread spilled (VGPR_Count=52 < 64 accs) ->
// VALUBusy 9.9%, latency-bound. R2: split the 64 output cols across 2
// threads per node (acc[32], wave-uniform half -> W loads become s_load /
// SGPR operands), 256-thr blocks, __launch_bounds__ to forbid re-spill.

#define NF   256     // node features (K dim)
#define NOUT 64      // 32 z-gate cols | 32 h-tilde cols
#define TN   128     // nodes per block
#define BK   64      // K-chunk staged in LDS
#define ROWPAD (BK + 1)     // 65: odd stride -> conflict-free LDS
#define NTHR 256            // 2 threads per node

// ---- prep: fold the two diffusion-direction weight matrices into W[256][64]
__global__ void prep_W(const float* __restrict__ wz,   // (2, 288, 32)
                       const float* __restrict__ wh,   // (2, 288, 32)
                       float* __restrict__ W)          // [256][64] row-major
{
    int idx = blockIdx.x * blockDim.x + threadIdx.x;   // 0 .. 16383
    if (idx >= NF * NOUT) return;
    int k = idx >> 6;          // feature row, 0..255
    int o = idx & 63;          // output col, 0..63
    const int PLANE = 288 * 32;
    float v;
    if (o < 32) v = wz[k * 32 + o]        + wz[PLANE + k * 32 + o];
    else        v = wh[k * 32 + (o - 32)] + wh[PLANE + k * 32 + (o - 32)];
    W[idx] = v;
}

__device__ __forceinline__ float fast_sigmoid(float v) {
    return 1.0f / (1.0f + __expf(-v));
}
__device__ __forceinline__ float fast_tanh(float v) {
    // tanh(v) = 1 - 2/(exp(2v)+1); saturates correctly at +/-1 for large |v|
    return 1.0f - 2.0f / (1.0f + __expf(2.0f * v));
}

__global__ void __launch_bounds__(NTHR, 2)
rgcn_main(const float* __restrict__ x,     // [N, 256]
          const float* __restrict__ W,     // [256][64] (ws)
          const float* __restrict__ bz,    // [32]
          const float* __restrict__ bh,    // [32]
          const float* __restrict__ fc1w,  // [32][32] (in,out)
          const float* __restrict__ fc1b,  // [32]
          const float* __restrict__ fc2w,  // [32]
          const float* __restrict__ fc2b,  // [1]
          float* __restrict__ out,         // [N]
          int n_nodes)
{
    __shared__ float Xs[TN * ROWPAD];      // 128*65*4 = 33.3 KB

    const int tid   = threadIdx.x;
    const int nl    = tid & (TN - 1);            // local node 0..127
    // wave-uniform (waves are 64 consecutive tids): force scalar so the
    // W-row pointer is uniform -> s_load_dwordx4, W values live in SGPRs.
    const int half  = __builtin_amdgcn_readfirstlane(tid >> 7);  // 0 | 1
    const int node0 = blockIdx.x * TN;
    const int node  = node0 + nl;

    float acc[32];
#pragma unroll
    for (int i = 0; i < 32; ++i) acc[i] = 0.0f;

    const float* Wh = W + half * 32;             // this thread's 32 cols

    for (int k0 = 0; k0 < NF; k0 += BK) {
        __syncthreads();
        // Stage TN x BK floats = 2048 float4s; 8 per thread.
        // 16 float4-slots per row: 16 consecutive lanes cover one 256 B
        // row segment -> fully coalesced.
#pragma unroll
        for (int i = 0; i < 8; ++i) {
            int q  = tid + i * NTHR;
            int nn = q >> 4;            // 0..127
            int kk = q & 15;            // float4 slot in row
            float4 v = make_float4(0.f, 0.f, 0.f, 0.f);
            int gn = node0 + nn;
            if (gn < n_nodes)
                v = *(const float4*)(x + (size_t)gn * NF + k0 + kk * 4);
            float* dst = &Xs[nn * ROWPAD + kk * 4];
            dst[0] = v.x; dst[1] = v.y; dst[2] = v.z; dst[3] = v.w;
        }
        __syncthreads();

        for (int k = 0; k < BK; ++k) {
            float a = Xs[nl * ROWPAD + k];       // lane stride 65%32=1: clean
            const float4* wr = (const float4*)(Wh + (size_t)(k0 + k) * NOUT);
#pragma unroll
            for (int o4 = 0; o4 < 8; ++o4) {
                float4 w = wr[o4];               // uniform -> SGPR values
                acc[o4 * 4 + 0] = fmaf(a, w.x, acc[o4 * 4 + 0]);
                acc[o4 * 4 + 1] = fmaf(a, w.y, acc[o4 * 4 + 1]);
                acc[o4 * 4 + 2] = fmaf(a, w.z, acc[o4 * 4 + 2]);
                acc[o4 * 4 + 3] = fmaf(a, w.w, acc[o4 * 4 + 3]);
            }
        }
    }

    // ---- epilogue: exchange t-half through LDS (reuse Xs), combine, fc head
    __syncthreads();                     // all lanes done reading Xs
    float* Hs = Xs;                      // 128*33 floats <= Xs capacity

    if (half == 1 && node < n_nodes) {
#pragma unroll
        for (int o = 0; o < 32; ++o)
            Hs[nl * 33 + o] = fast_tanh(acc[o] + bh[o]);
    }
    __syncthreads();

    if (half == 0 && node < n_nodes) {
        float h[32];
#pragma unroll
        for (int o = 0; o < 32; ++o) {
            float z = fast_sigmoid(acc[o] + bz[o]);
            h[o] = (1.0f - z) * Hs[nl * 33 + o];
        }
        float oacc = fc2b[0];
        for (int j = 0; j < 32; ++j) {
            float s = fc1b[j];
#pragma unroll
            for (int o = 0; o < 32; ++o)
                s = fmaf(h[o], fc1w[o * 32 + j], s);   // uniform -> SGPR
            s = fmaxf(s, 0.0f);
            oacc = fmaf(s, fc2w[j], oacc);
        }
        out[node] = fast_sigmoid(oacc);  // tids 0..127 -> coalesced store
    }
}

extern "C" void kernel_launch(void* const* d_in, const int* in_sizes, int n_in,
                              void* d_out, int out_size, void* d_ws, size_t ws_size,
                              hipStream_t stream) {
    // setup_inputs order:
    // 0:x 1:edge_index(dead) 2:w_z 3:b_z 4:w_r(dead) 5:b_r(dead)
    // 6:w_h 7:b_h 8:fc1_w 9:fc1_b 10:fc2_w 11:fc2_b
    const float* x    = (const float*)d_in[0];
    const float* wz   = (const float*)d_in[2];
    const float* bz   = (const float*)d_in[3];
    const float* wh   = (const float*)d_in[6];
    const float* bh   = (const float*)d_in[7];
    const float* fc1w = (const float*)d_in[8];
    const float* fc1b = (const float*)d_in[9];
    const float* fc2w = (const float*)d_in[10];
    const float* fc2b = (const float*)d_in[11];
    float* out = (float*)d_out;
    float* W   = (float*)d_ws;   // 256*64*4 = 64 KB

    const int n = in_sizes[0] / NF;   // 100000

    prep_W<<<(NF * NOUT + 255) / 256, 256, 0, stream>>>(wz, wh, W);
    rgcn_main<<<(n + TN - 1) / TN, NTHR, 0, stream>>>(
        x, W, bz, bh, fc1w, fc1b, fc2w, fc2b, out, n);
}

// Round 3
// 220.138 us; speedup vs baseline: 1.9229x; 1.1222x over previous
//
#include <hip/hip_runtime.h>
#include <hip/hip_bf16.h>

// Reduction of the reference (h0 = 0):
//   z  = sigmoid(x @ Wz + bz),  Wz = (w_z[0]+w_z[1])[:256,:]
//   t  = tanh   (x @ Wh + bh),  Wh = (w_h[0]+w_h[1])[:256,:]
//   h  = (1-z) * t
//   hid= relu(h @ fc1_w + fc1_b)
//   out= sigmoid(hid @ fc2_w + fc2_b)
// w_r/b_r and edge_index are dead. Main cost: [100000,256] @ [256,64] fp32.
//
// R2 post-mortem: W rows via wave-uniform global loads -> 8 s_load_dwordx4
// per k sharing lgkmcnt with ds_read; VALUBusy 27%, latency-bound on the
// scalar-load queue. R3: both operands in LDS, register-tiled 8 nodes x
// 4 cols per thread, X staged transposed so per-k reads are 3 ds_read_b128
// vs 32 v_fmac (VALU-bound by construction). W pre-permuted so each
// thread's col quad {2tx,2tx+1,2tx+32,2tx+33} is one contiguous float4
// (z-col and h-col paired -> gate combine stays in-register).

#define NF    256    // node features (K dim)
#define NOUT  64     // 32 z-gate cols | 32 h-tilde cols
#define MB    128    // nodes per block
#define BK    32     // K-chunk staged in LDS
#define NTHR  256
#define XPAD  132    // XsT row stride (floats): 132%32=4 -> conflict-free
#define WPAD  68     // Ws  row stride
#define HPAD  34     // Hs  row stride (even: keeps b64 writes 8B-aligned)
// LDS layout (floats): [0, 4224) XsT | [4224, 6400) Ws
// epilogue reuse:      [0, 4352) Hs  | [4352, 4480) Ps
#define S_FLOATS 6400

// ---- prep: fold + permute weights into Wp[256][64] where
// Wp[k][4*tx + m] = W[k][ 2*tx + (m&1) + 32*(m>>1) ]
__global__ void prep_W(const float* __restrict__ wz,   // (2, 288, 32)
                       const float* __restrict__ wh,   // (2, 288, 32)
                       float* __restrict__ Wp)         // [256][64] permuted
{
    int idx = blockIdx.x * blockDim.x + threadIdx.x;   // 0 .. 16383
    if (idx >= NF * NOUT) return;
    int k = idx >> 6;            // feature row, 0..255
    int j = idx & 63;            // permuted col
    int tx = j >> 2, m = j & 3;
    int o = 2 * tx + (m & 1) + ((m >> 1) << 5);        // original col 0..63
    const int PLANE = 288 * 32;
    float v;
    if (o < 32) v = wz[k * 32 + o]        + wz[PLANE + k * 32 + o];
    else        v = wh[k * 32 + (o - 32)] + wh[PLANE + k * 32 + (o - 32)];
    Wp[idx] = v;
}

__device__ __forceinline__ float fast_sigmoid(float v) {
    return 1.0f / (1.0f + __expf(-v));
}
__device__ __forceinline__ float fast_tanh(float v) {
    return 1.0f - 2.0f / (1.0f + __expf(2.0f * v));
}

__global__ void __launch_bounds__(NTHR, 4)
rgcn_main(const float* __restrict__ x,     // [N, 256]
          const float* __restrict__ Wp,    // [256][64] permuted (ws)
          const float* __restrict__ bz,    // [32]
          const float* __restrict__ bh,    // [32]
          const float* __restrict__ fc1w,  // [32][32] (in,out)
          const float* __restrict__ fc1b,  // [32]
          const float* __restrict__ fc2w,  // [32]
          const float* __restrict__ fc2b,  // [1]
          float* __restrict__ out,         // [N]
          int n_nodes)
{
    __shared__ float S[S_FLOATS];          // 25.6 KB
    float* XsT = S;                        // [BK][XPAD]  transposed X tile
    float* Ws  = S + BK * XPAD;            // [BK][WPAD]

    const int tid   = threadIdx.x;
    const int tx    = tid & 15;            // col-quad group 0..15
    const int ty    = tid >> 4;            // node group 0..15 (8 nodes each)
    const int node0 = blockIdx.x * MB;

    float acc[32];                         // [8 nodes][4 cols]
#pragma unroll
    for (int i = 0; i < 32; ++i) acc[i] = 0.0f;

    for (int k0 = 0; k0 < NF; k0 += BK) {
        __syncthreads();
        // ---- stage X transposed: 1024 float4s, 4 per thread.
        // Lanes: node=q>>3, slot=q&7 -> 8 lanes cover one 128 B row seg.
#pragma unroll
        for (int i = 0; i < 4; ++i) {
            int q    = tid + i * NTHR;
            int nn   = q >> 3;             // 0..127
            int slot = q & 7;              // k-slot (4 floats)
            float4 v = make_float4(0.f, 0.f, 0.f, 0.f);
            int gn = node0 + nn;
            if (gn < n_nodes)
                v = *(const float4*)(x + (size_t)gn * NF + k0 + slot * 4);
            XsT[(slot * 4 + 0) * XPAD + nn] = v.x;
            XsT[(slot * 4 + 1) * XPAD + nn] = v.y;
            XsT[(slot * 4 + 2) * XPAD + nn] = v.z;
            XsT[(slot * 4 + 3) * XPAD + nn] = v.w;
        }
        // ---- stage Wp chunk: 512 float4s, 2 per thread.
#pragma unroll
        for (int i = 0; i < 2; ++i) {
            int q  = tid + i * NTHR;
            int r  = q >> 4;               // row in chunk 0..31
            int cs = q & 15;               // float4 slot 0..15
            float4 v = *(const float4*)(Wp + (size_t)(k0 + r) * NOUT + cs * 4);
            *(float4*)(Ws + r * WPAD + cs * 4) = v;
        }
        __syncthreads();

#pragma unroll
        for (int k = 0; k < BK; ++k) {
            const float* xr = XsT + k * XPAD + ty * 8;
            float4 a0 = *(const float4*)(xr);
            float4 a1 = *(const float4*)(xr + 4);
            float4 w  = *(const float4*)(Ws + k * WPAD + tx * 4);
            float a[8] = {a0.x, a0.y, a0.z, a0.w, a1.x, a1.y, a1.z, a1.w};
#pragma unroll
            for (int i = 0; i < 8; ++i) {
                acc[i * 4 + 0] = fmaf(a[i], w.x, acc[i * 4 + 0]);
                acc[i * 4 + 1] = fmaf(a[i], w.y, acc[i * 4 + 1]);
                acc[i * 4 + 2] = fmaf(a[i], w.z, acc[i * 4 + 2]);
                acc[i * 4 + 3] = fmaf(a[i], w.w, acc[i * 4 + 3]);
            }
        }
    }

    // ---- epilogue: gates in-register, h through LDS, split fc head
    __syncthreads();                       // XsT/Ws dead from here
    float* Hs = S;                         // [MB][HPAD]
    float* Ps = S + MB * HPAD;             // [MB]

    const float bz0 = bz[2 * tx], bz1 = bz[2 * tx + 1];
    const float bh0 = bh[2 * tx], bh1 = bh[2 * tx + 1];
#pragma unroll
    for (int i = 0; i < 8; ++i) {
        int nl = ty * 8 + i;
        float z0 = fast_sigmoid(acc[i * 4 + 0] + bz0);
        float z1 = fast_sigmoid(acc[i * 4 + 1] + bz1);
        float t0 = fast_tanh   (acc[i * 4 + 2] + bh0);
        float t1 = fast_tanh   (acc[i * 4 + 3] + bh1);
        Hs[nl * HPAD + 2 * tx]     = (1.0f - z0) * t0;
        Hs[nl * HPAD + 2 * tx + 1] = (1.0f - z1) * t1;
    }
    __syncthreads();

    const int nl   = tid & (MB - 1);
    const int half = tid >> 7;             // j-range half
    float h[32];
#pragma unroll
    for (int m = 0; m < 8; ++m) {
        float4 v = *(const float4*)(Hs + nl * HPAD + m * 4);
        h[m * 4 + 0] = v.x; h[m * 4 + 1] = v.y;
        h[m * 4 + 2] = v.z; h[m * 4 + 3] = v.w;
    }
    float part = 0.0f;
    for (int jj = 0; jj < 16; ++jj) {
        int j = half * 16 + jj;
        float s = fc1b[j];
#pragma unroll
        for (int o = 0; o < 32; ++o)
            s = fmaf(h[o], fc1w[o * 32 + j], s);   // uniform -> scalar loads
        part = fmaf(fmaxf(s, 0.0f), fc2w[j], part);
    }
    if (half == 1) Ps[nl] = part;
    __syncthreads();
    if (half == 0) {
        int gn = node0 + nl;
        if (gn < n_nodes)
            out[gn] = fast_sigmoid(part + Ps[nl] + fc2b[0]);
    }
}

extern "C" void kernel_launch(void* const* d_in, const int* in_sizes, int n_in,
                              void* d_out, int out_size, void* d_ws, size_t ws_size,
                              hipStream_t stream) {
    // setup_inputs order:
    // 0:x 1:edge_index(dead) 2:w_z 3:b_z 4:w_r(dead) 5:b_r(dead)
    // 6:w_h 7:b_h 8:fc1_w 9:fc1_b 10:fc2_w 11:fc2_b
    const float* x    = (const float*)d_in[0];
    const float* wz   = (const float*)d_in[2];
    const float* bz   = (const float*)d_in[3];
    const float* wh   = (const float*)d_in[6];
    const float* bh   = (const float*)d_in[7];
    const float* fc1w = (const float*)d_in[8];
    const float* fc1b = (const float*)d_in[9];
    const float* fc2w = (const float*)d_in[10];
    const float* fc2b = (const float*)d_in[11];
    float* out = (float*)d_out;
    float* Wp  = (float*)d_ws;   // 256*64*4 = 64 KB

    const int n = in_sizes[0] / NF;   // 100000

    prep_W<<<(NF * NOUT + 255) / 256, 256, 0, stream>>>(wz, wh, Wp);
    rgcn_main<<<(n + MB - 1) / MB, NTHR, 0, stream>>>(
        x, Wp, bz, bh, fc1w, fc1b, fc2w, fc2b, out, n);
}

// Round 4
// 206.569 us; speedup vs baseline: 2.0492x; 1.0657x over previous
//
#include <hip/hip_runtime.h>
#include <hip/hip_bf16.h>

// Reduction of the reference (h0 = 0):
//   z  = sigmoid(x @ Wz + bz),  t = tanh(x @ Wh + bh),  h = (1-z)*t
//   out= sigmoid(relu(h @ fc1) @ fc2)       (w_r/b_r, edge_index dead)
// Main cost: [100000,256] @ [256,64]. R3 post-mortem: fp32 register-tile is
// LDS-read-BW-bound (3 b128/32 FMA -> VALUBusy capped ~48%). R4: bf16 MFMA
// (v_mfma_f32_32x32x16_bf16) -> compute off VALU; kernel becomes a
// streaming convert+stage bound by the 102 MB read of x (floor ~16.3 us).
// W pre-swizzled into B-fragment order by prep -> B-frags are coalesced
// global dwordx4 (L2-resident), no LDS for B.

#define NF     256
#define NOUT   64
#define MB     128          // nodes per block
#define NTHR   256          // 4 waves
#define KCHUNK 128          // bf16 X-chunk staged in LDS
#define XSTR   132          // Xb row stride in bf16 (264 B: 8B-aligned, ~2-way)
#define HPAD   36           // Hs row stride in floats (16B-aligned rows)

typedef __attribute__((ext_vector_type(8)))  short  short8;
typedef __attribute__((ext_vector_type(16))) float  floatx16;

__device__ __forceinline__ unsigned f2bf(float f) {
    __hip_bfloat16 h = __float2bfloat16(f);   // RNE
    return (unsigned)*(unsigned short*)&h;
}
__device__ __forceinline__ float fast_sigmoid(float v) {
    return 1.0f / (1.0f + __expf(-v));
}
__device__ __forceinline__ float fast_tanh(float v) {
    return 1.0f - 2.0f / (1.0f + __expf(2.0f * v));
}

// ---- prep: fold w[0]+w[1], emit bf16 in 32x32x16 B-fragment order:
// Wf[((kt*2+nt)*64 + lane)*8 + j] = W[kt*16 + (lane>>5)*8 + j][nt*32 + (lane&31)]
__global__ void prep_W(const float* __restrict__ wz,   // (2, 288, 32)
                       const float* __restrict__ wh,   // (2, 288, 32)
                       unsigned short* __restrict__ Wf) // 16*2*64*8 bf16
{
    int idx = blockIdx.x * blockDim.x + threadIdx.x;   // 0 .. 16383
    if (idx >= NF * NOUT) return;
    int j    = idx & 7;
    int lane = (idx >> 3) & 63;
    int nt   = (idx >> 9) & 1;
    int kt   = idx >> 10;                  // 0..15
    int k = kt * 16 + (lane >> 5) * 8 + j; // 0..255
    int o = nt * 32 + (lane & 31);         // 0..63
    const int PLANE = 288 * 32;
    float v;
    if (o < 32) v = wz[k * 32 + o]        + wz[PLANE + k * 32 + o];
    else        v = wh[k * 32 + (o - 32)] + wh[PLANE + k * 32 + (o - 32)];
    Wf[idx] = (unsigned short)f2bf(v);
}

__global__ void __launch_bounds__(NTHR, 4)
rgcn_main(const float* __restrict__ x,     // [N, 256]
          const unsigned short* __restrict__ Wf, // B-frags (ws)
          const float* __restrict__ bz,    // [32]
          const float* __restrict__ bh,    // [32]
          const float* __restrict__ fc1w,  // [32][32] (in,out)
          const float* __restrict__ fc1b,  // [32]
          const float* __restrict__ fc2w,  // [32]
          const float* __restrict__ fc2b,  // [1]
          float* __restrict__ out,         // [N]
          int n_nodes)
{
    __shared__ __align__(16) char S[MB * XSTR * 2];   // 33792 B
    unsigned short* Xb = (unsigned short*)S;          // [MB][XSTR] bf16
    float* Hs = (float*)S;                            // [MB][HPAD] (epilogue)
    float* Ps = (float*)(S + MB * HPAD * 4);          // [MB]

    const int tid   = threadIdx.x;
    const int lane  = tid & 63;
    const int wave  = tid >> 6;            // 0..3
    const int wb    = wave * 32;           // wave's node base
    const int node0 = blockIdx.x * MB;

    floatx16 acc0 = {};                    // z cols (nt=0)
    floatx16 acc1 = {};                    // h cols (nt=1)

    for (int c = 0; c < 2; ++c) {
        __syncthreads();
        // ---- stage 128 nodes x 128 floats -> bf16 LDS. 16 iters x 4 KB.
        // lanes: slot = tid&31 (16 B each) -> 512 B contiguous per row-half.
#pragma unroll
        for (int i = 0; i < 16; ++i) {
            int nn   = (tid >> 5) + i * 8;         // 0..127
            int slot = tid & 31;                   // float4 slot
            float4 v = make_float4(0.f, 0.f, 0.f, 0.f);
            int gn = node0 + nn;
            if (gn < n_nodes)
                v = *(const float4*)(x + (size_t)gn * NF + c * KCHUNK + slot * 4);
            unsigned lo = f2bf(v.x) | (f2bf(v.y) << 16);
            unsigned hi = f2bf(v.z) | (f2bf(v.w) << 16);
            *(uint2*)(Xb + nn * XSTR + slot * 4) = make_uint2(lo, hi);
        }
        __syncthreads();

        // ---- 8 k-steps of 32x32x16 MFMA
#pragma unroll
        for (int kt = 0; kt < 8; ++kt) {
            int ktg = c * 8 + kt;
            // B-frags direct from global (pre-swizzled, L2-hot): 16 B/lane
            const uint4* bp = (const uint4*)Wf + (size_t)(ktg * 2) * 64 + lane;
            uint4 b0u = bp[0];
            uint4 b1u = bp[64];
            // A-frag from LDS: node = wb + (lane&31), 8 bf16 along k
            const unsigned short* ap =
                Xb + (wb + (lane & 31)) * XSTR + kt * 16 + (lane >> 5) * 8;
            uint2 alo = *(const uint2*)(ap);
            uint2 ahi = *(const uint2*)(ap + 4);
            union { short8 s; uint2 u[2]; } a, b0, b1;
            a.u[0] = alo; a.u[1] = ahi;
            b0.u[0] = make_uint2(b0u.x, b0u.y); b0.u[1] = make_uint2(b0u.z, b0u.w);
            b1.u[0] = make_uint2(b1u.x, b1u.y); b1.u[1] = make_uint2(b1u.z, b1u.w);
            acc0 = __builtin_amdgcn_mfma_f32_32x32x16_bf16(a.s, b0.s, acc0, 0, 0, 0);
            acc1 = __builtin_amdgcn_mfma_f32_32x32x16_bf16(a.s, b1.s, acc1, 0, 0, 0);
        }
    }

    // ---- epilogue: gates in-register (C/D: col=lane&31,
    // row=(reg&3)+8*(reg>>2)+4*(lane>>5)), h -> LDS, fc head.
    const int nc   = lane & 31;            // output col within 32
    const float bzn = bz[nc];
    const float bhn = bh[nc];
    __syncthreads();                       // Xb dead from here
#pragma unroll
    for (int r = 0; r < 16; ++r) {
        int row = (r & 3) + 8 * (r >> 2) + 4 * (lane >> 5);
        float z = fast_sigmoid(acc0[r] + bzn);
        float t = fast_tanh   (acc1[r] + bhn);
        Hs[(wb + row) * HPAD + nc] = (1.0f - z) * t;
    }
    __syncthreads();

    const int nl   = tid & (MB - 1);
    const int half = tid >> 7;             // fc1 j-range half
    float h[32];
#pragma unroll
    for (int m = 0; m < 8; ++m) {
        float4 v = *(const float4*)(Hs + nl * HPAD + m * 4);
        h[m * 4 + 0] = v.x; h[m * 4 + 1] = v.y;
        h[m * 4 + 2] = v.z; h[m * 4 + 3] = v.w;
    }
    float part = 0.0f;
    for (int jj = 0; jj < 16; ++jj) {
        int j = half * 16 + jj;            // wave-uniform -> scalar loads
        float s = fc1b[j];
#pragma unroll
        for (int o = 0; o < 32; ++o)
            s = fmaf(h[o], fc1w[o * 32 + j], s);
        part = fmaf(fmaxf(s, 0.0f), fc2w[j], part);
    }
    if (half == 1) Ps[nl] = part;
    __syncthreads();
    if (half == 0) {
        int gn = node0 + nl;
        if (gn < n_nodes)
            out[gn] = fast_sigmoid(part + Ps[nl] + fc2b[0]);
    }
}

extern "C" void kernel_launch(void* const* d_in, const int* in_sizes, int n_in,
                              void* d_out, int out_size, void* d_ws, size_t ws_size,
                              hipStream_t stream) {
    // 0:x 1:edge_index(dead) 2:w_z 3:b_z 4:w_r(dead) 5:b_r(dead)
    // 6:w_h 7:b_h 8:fc1_w 9:fc1_b 10:fc2_w 11:fc2_b
    const float* x    = (const float*)d_in[0];
    const float* wz   = (const float*)d_in[2];
    const float* bz   = (const float*)d_in[3];
    const float* wh   = (const float*)d_in[6];
    const float* bh   = (const float*)d_in[7];
    const float* fc1w = (const float*)d_in[8];
    const float* fc1b = (const float*)d_in[9];
    const float* fc2w = (const float*)d_in[10];
    const float* fc2b = (const float*)d_in[11];
    float* out = (float*)d_out;
    unsigned short* Wf = (unsigned short*)d_ws;   // 32 KB of B-fragments

    const int n = in_sizes[0] / NF;   // 100000

    prep_W<<<(NF * NOUT + 255) / 256, 256, 0, stream>>>(wz, wh, Wf);
    rgcn_main<<<(n + MB - 1) / MB, NTHR, 0, stream>>>(
        x, Wf, bz, bh, fc1w, fc1b, fc2w, fc2b, out, n);
}